// Round 14
// baseline (358.976 us; speedup 1.0000x reference)
//
#include <hip/hip_runtime.h>

// Dims
#define NB 4
#define NTOK 32768
#define BNT 131072      // NB*NTOK
#define CDIM 256
#define HH 8
#define NCOL 768        // 256 fx cols + 512 proj cols

typedef _Float16 f16;
typedef __attribute__((ext_vector_type(8))) _Float16 f16x8;
typedef __attribute__((ext_vector_type(4))) _Float16 f16x4;
typedef __attribute__((ext_vector_type(4))) float f32x4;

__device__ inline void gload_lds16(const void* g, void* l) {
    __builtin_amdgcn_global_load_lds(
        (const __attribute__((address_space(1))) void*)g,
        (__attribute__((address_space(3))) void*)l, 16, 0, 0);
}

// ---------------- K0: build combined weight matrix (f16, transposed) ----------------
__global__ __launch_bounds__(256) void k0_build(
    const float* __restrict__ Wx, const float* __restrict__ bx,
    const float* __restrict__ Wfx, const float* __restrict__ bfx,
    const float* __restrict__ Wslice, const float* __restrict__ bslice,
    f16* __restrict__ Bt, float* __restrict__ bcomb)
{
    int col = blockIdx.x;      // 0..767 (output column n)
    int k = threadIdx.x;       // 0..255 (input channel)
    float acc;
    if (col < 256) {
        acc = Wfx[col * 256 + k];
        if (k == 0) bcomb[col] = bfx[col];
    } else {
        int p = col - 256, h = p >> 6, s = p & 63;
        acc = 0.f;
        #pragma unroll
        for (int d = 0; d < 32; ++d)
            acc += Wx[(h * 32 + d) * 256 + k] * Wslice[s * 32 + d];
        if (k == 0) {
            float bacc = bslice[s];
            #pragma unroll
            for (int d = 0; d < 32; ++d)
                bacc += bx[h * 32 + d] * Wslice[s * 32 + d];
            bcomb[col] = bacc;
        }
    }
    Bt[(long)col * 256 + k] = (f16)acc;
}

// ---------------- K1a: 128m x 256n, 8 waves, BK=32, A = fp32 reg-staged ----------------
// A fp32 [M][256]: per K-step each thread does 2x global_load_dwordx4 -> 8 casts
// -> 1 ds_write_b128 at the DEST-swizzled offset (same involution as reads).
// B f16 [N][KO] staged via gload_lds (source pre-swizzled). 3-buffer LDS,
// depth-2 prefetch, 1 raw s_barrier/step. writeA(cs+2) placed AFTER compute(cs):
// its compiler wait for the A-regs (FIFO-older than B(cs+2)) transitively drains
// B(cs+1); buf (cs+2)%3 == (cs-1)%3 is idle (all waves passed prev barrier).
// Fused temp-softmax epilogue. XCD-bijective block swizzle (nwg%8==0).
template<int NSO>
__global__ __launch_bounds__(512) void gemm_wx(
    const float* __restrict__ A32, const f16* __restrict__ Bt,
    const float* __restrict__ bias, f16* __restrict__ Cfx,
    f16* __restrict__ Cw, const float* __restrict__ temperature)
{
    constexpr int KO = NSO * 32;
    __shared__ char lds[73728];   // 3 x (A 8KB | B 16KB)

    const int tid = threadIdx.x;
    const int lane = tid & 63;
    const int w = tid >> 6;        // 0..7
    const int wm = w >> 2, wn = w & 3;

    // XCD-aware bijective swizzle
    const int nx = gridDim.x;
    const int nwg = nx * gridDim.y;
    const int lid = blockIdx.y * nx + blockIdx.x;
    const int swz = (lid & 7) * (nwg >> 3) + (lid >> 3);
    const int m0 = (swz / nx) * 128, n0 = (swz % nx) * 256;

    f32x4 acc[4][4] = {};

    // A staging geometry: row ar (0..127), 16B-f16 chunk ac (0..3)
    const int ar = tid >> 2, ac = tid & 3;
    const float* Asrc = A32 + (long)(m0 + ar) * CDIM + ac * 8;
    const int aoff = ar * 64 + ((ac ^ ((ar >> 1) & 3)) << 4);  // dest-swizzled

    auto loadA = [&](int cs, float4& v0, float4& v1) {
        v0 = *(const float4*)(Asrc + cs * 32);
        v1 = *(const float4*)(Asrc + cs * 32 + 4);
    };
    auto writeA = [&](int buf, const float4& v0, const float4& v1) {
        f16x8 o = {(f16)v0.x, (f16)v0.y, (f16)v0.z, (f16)v0.w,
                   (f16)v1.x, (f16)v1.y, (f16)v1.z, (f16)v1.w};
        *(f16x8*)(lds + buf * 24576 + aoff) = o;
    };
    auto stageB = [&](int cs, int buf) {
        char* base = lds + buf * 24576;
        #pragma unroll
        for (int i = 0; i < 2; ++i) {   // 2 slots per wave: r in 0..255
            int q = (w * 2 + i) * 64 + lane;
            int r = q >> 2, c = q & 3;
            int csrc = c ^ ((r >> 1) & 3);
            gload_lds16(Bt + (long)(n0 + r) * KO + cs * 32 + csrc * 8,
                        base + 8192 + (w * 2 + i) * 1024);
        }
    };

    // prologue: tiles 0 and 1
    {
        float4 a0v0, a0v1, a1v0, a1v1;
        loadA(0, a0v0, a0v1); stageB(0, 0);
        loadA(1, a1v0, a1v1); stageB(1, 1);
        writeA(0, a0v0, a0v1);   // waits A(0) regs
        writeA(1, a1v0, a1v1);   // waits A(1) regs -> drains B(0) too
        asm volatile("s_waitcnt vmcnt(2) lgkmcnt(0)" ::: "memory");
        __builtin_amdgcn_sched_barrier(0);
        __builtin_amdgcn_s_barrier();
    }

    for (int cs = 0; cs < NSO; ++cs) {
        const bool st = (cs + 2 < NSO);
        float4 v0, v1;
        if (st) { loadA(cs + 2, v0, v1); stageB(cs + 2, (cs + 2) % 3); }

        const char* sa = lds + (cs % 3) * 24576;
        const char* sb = sa + 8192;
        const int cr = lane >> 4;
        f16x8 a[4], b[4];
        #pragma unroll
        for (int mi = 0; mi < 4; ++mi) {
            int r = wm * 64 + mi * 16 + (lane & 15);
            a[mi] = *(const f16x8*)(sa + r * 64 + ((cr ^ ((r >> 1) & 3)) << 4));
        }
        #pragma unroll
        for (int ni = 0; ni < 4; ++ni) {
            int r = wn * 64 + ni * 16 + (lane & 15);
            b[ni] = *(const f16x8*)(sb + r * 64 + ((cr ^ ((r >> 1) & 3)) << 4));
        }
        #pragma unroll
        for (int mi = 0; mi < 4; ++mi)
            #pragma unroll
            for (int ni = 0; ni < 4; ++ni)
                acc[mi][ni] = __builtin_amdgcn_mfma_f32_16x16x32_f16(
                    a[mi], b[ni], acc[mi][ni], 0, 0, 0);

        if (st) writeA((cs + 2) % 3, v0, v1);   // auto-wait A regs -> drains B(cs+1)

        if (cs + 1 < NSO) {
            if (st) asm volatile("s_waitcnt vmcnt(2) lgkmcnt(0)" ::: "memory");
            else    asm volatile("s_waitcnt vmcnt(0) lgkmcnt(0)" ::: "memory");
            __builtin_amdgcn_sched_barrier(0);
            __builtin_amdgcn_s_barrier();
        }
    }

    // --- epilogue: C/D layout col=lane&15, row=(lane>>4)*4+reg ---
    {
        int rbase = m0 + wm * 64 + (lane >> 4) * 4;
        int cbase = n0 + wn * 64 + (lane & 15);
        float bv[4];
        #pragma unroll
        for (int ni = 0; ni < 4; ++ni) bv[ni] = bias[cbase + ni * 16];

        if (n0 > 0) {   // proj cols; wave's 64-col span = one head
            int h = ((n0 - 256) >> 6) + wn;
            float invt = 1.f / fminf(fmaxf(temperature[h], 0.5f), 5.0f);
            #pragma unroll
            for (int mi = 0; mi < 4; ++mi)
                #pragma unroll
                for (int rr = 0; rr < 4; ++rr) {
                    float v[4];
                    #pragma unroll
                    for (int ni = 0; ni < 4; ++ni)
                        v[ni] = (acc[mi][ni][rr] + bv[ni]) * invt;
                    float m = fmaxf(fmaxf(v[0], v[1]), fmaxf(v[2], v[3]));
                    #pragma unroll
                    for (int o = 1; o < 16; o <<= 1) m = fmaxf(m, __shfl_xor(m, o));
                    float e[4], ssum = 0.f;
                    #pragma unroll
                    for (int ni = 0; ni < 4; ++ni) { e[ni] = __expf(v[ni] - m); ssum += e[ni]; }
                    #pragma unroll
                    for (int o = 1; o < 16; o <<= 1) ssum += __shfl_xor(ssum, o);
                    float rs = 1.f / ssum;
                    long row = rbase + mi * 16 + rr;
                    #pragma unroll
                    for (int ni = 0; ni < 4; ++ni)
                        Cw[row * 512 + cbase + ni * 16 - 256] = (f16)(e[ni] * rs);
                }
        } else {        // fx cols
            #pragma unroll
            for (int mi = 0; mi < 4; ++mi)
                #pragma unroll
                for (int rr = 0; rr < 4; ++rr) {
                    long row = rbase + mi * 16 + rr;
                    #pragma unroll
                    for (int ni = 0; ni < 4; ++ni)
                        Cfx[row * 256 + cbase + ni * 16] =
                            (f16)(acc[mi][ni][rr] + bv[ni]);
                }
        }
    }
}

// ---------------- K4 GEMM (round-10/13 proven): 128m x 256n, 8 waves, BK=32 ----
template<int NSO>
__global__ __launch_bounds__(512) void gemm_w(
    const f16* __restrict__ A, const f16* __restrict__ Bt,
    const float* __restrict__ bias, float* __restrict__ Cf, long bStrideB)
{
    constexpr int KO = NSO * 32;
    __shared__ char lds[73728];   // 3 x (A 8KB | B 16KB)

    const int tid = threadIdx.x;
    const int lane = tid & 63;
    const int w = tid >> 6;        // 0..7
    const int wm = w >> 2, wn = w & 3;

    const int nx = gridDim.x;
    const int nwg = nx * gridDim.y;
    const int lid = blockIdx.y * nx + blockIdx.x;
    const int swz = (lid & 7) * (nwg >> 3) + (lid >> 3);
    const int m0 = (swz / nx) * 128, n0 = (swz % nx) * 256;

    const f16* BtB = Bt + ((long)m0 >> 15) * bStrideB;

    f32x4 acc[4][4] = {};

    auto stage = [&](int cs, int buf) {
        char* base = lds + buf * 24576;
        {
            int r = tid >> 2, c = tid & 3;
            int csrc = c ^ ((r >> 1) & 3);
            gload_lds16(A + (long)(m0 + r) * KO + cs * 32 + csrc * 8,
                        base + (tid & ~63) * 16);
        }
        #pragma unroll
        for (int i = 0; i < 2; ++i) {
            int q = (w * 2 + i) * 64 + lane;
            int r = q >> 2, c = q & 3;
            int csrc = c ^ ((r >> 1) & 3);
            gload_lds16(BtB + (long)(n0 + r) * KO + cs * 32 + csrc * 8,
                        base + 8192 + (w * 2 + i) * 1024);
        }
    };

    stage(0, 0);
    stage(1, 1);
    asm volatile("s_waitcnt vmcnt(3)" ::: "memory");
    __builtin_amdgcn_sched_barrier(0);
    __builtin_amdgcn_s_barrier();

    for (int cs = 0; cs < NSO; ++cs) {
        const int buf = cs % 3;
        if (cs + 2 < NSO) stage(cs + 2, (cs + 2) % 3);
        const char* sa = lds + buf * 24576;
        const char* sb = sa + 8192;
        const int cr = lane >> 4;
        f16x8 a[4], b[4];
        #pragma unroll
        for (int mi = 0; mi < 4; ++mi) {
            int r = wm * 64 + mi * 16 + (lane & 15);
            a[mi] = *(const f16x8*)(sa + r * 64 + ((cr ^ ((r >> 1) & 3)) << 4));
        }
        #pragma unroll
        for (int ni = 0; ni < 4; ++ni) {
            int r = wn * 64 + ni * 16 + (lane & 15);
            b[ni] = *(const f16x8*)(sb + r * 64 + ((cr ^ ((r >> 1) & 3)) << 4));
        }
        #pragma unroll
        for (int mi = 0; mi < 4; ++mi)
            #pragma unroll
            for (int ni = 0; ni < 4; ++ni)
                acc[mi][ni] = __builtin_amdgcn_mfma_f32_16x16x32_f16(
                    a[mi], b[ni], acc[mi][ni], 0, 0, 0);
        if (cs + 1 < NSO) {
            if (cs + 2 < NSO) asm volatile("s_waitcnt vmcnt(3)" ::: "memory");
            else              asm volatile("s_waitcnt vmcnt(0)" ::: "memory");
            __builtin_amdgcn_sched_barrier(0);
            __builtin_amdgcn_s_barrier();
        }
    }

    {
        int rbase = m0 + wm * 64 + (lane >> 4) * 4;
        int cbase = n0 + wn * 64 + (lane & 15);
        float bv[4];
        #pragma unroll
        for (int ni = 0; ni < 4; ++ni) bv[ni] = bias[cbase + ni * 16];
        #pragma unroll
        for (int mi = 0; mi < 4; ++mi)
            #pragma unroll
            for (int ni = 0; ni < 4; ++ni)
                #pragma unroll
                for (int rr = 0; rr < 4; ++rr)
                    Cf[(long)(rbase + mi * 16 + rr) * 256 + cbase + ni * 16] =
                        acc[mi][ni][rr] + bv[ni];
    }
}

// ---------------- K1c (MFMA): slice_token + slice_norm partials via matrix pipe ----
__global__ __launch_bounds__(256) void k1c_mfma(
    const f16* __restrict__ yfx, const f16* __restrict__ yw,
    float* __restrict__ partials)
{
    __shared__ char lds[49152];

    const int tid = threadIdx.x;
    const int lane = tid & 63;
    const int wv = tid >> 6;
    const int chunk64 = blockIdx.x & 63;
    const int bh = blockIdx.x >> 6;
    const int b = bh >> 3, h = bh & 7;
    const long tbase = (long)b * NTOK + (long)chunk64 * 512;

    f32x4 acc[4][3] = {};

    const f16 oe = ((lane & 15) == 0) ? (f16)1.0f : (f16)0.0f;
    const f16x8 bones = {oe, oe, oe, oe, oe, oe, oe, oe};
    const int g = lane >> 4;

    auto stage = [&](int iter, int buf) {
        const long t0 = tbase + iter * 128;
        char* base = lds + buf * 24576;
        #pragma unroll
        for (int i = 0; i < 4; ++i) {
            int k = wv * 4 + i;
            int sc = (lane & 7) ^ ((k & 3) << 1);
            gload_lds16(yw + (t0 + k * 8 + (lane >> 3)) * 512 + h * 64 + sc * 8,
                        base + k * 1024);
        }
        #pragma unroll
        for (int i = 0; i < 2; ++i) {
            int k = wv * 2 + i;
            int tq = (k & 1) * 16 + (lane >> 2);
            int dc = (lane & 3) ^ ((tq >> 3) & 3);
            gload_lds16(yfx + (t0 + k * 16 + (lane >> 2)) * 256 + h * 32 + dc * 8,
                        base + 16384 + k * 1024);
        }
    };

    stage(0, 0);
    for (int iter = 0; iter < 4; ++iter) {
        const int buf = iter & 1;
        if (iter < 3) {
            stage(iter + 1, buf ^ 1);
            asm volatile("s_waitcnt vmcnt(6)" ::: "memory");
        } else {
            asm volatile("s_waitcnt vmcnt(0)" ::: "memory");
        }
        __builtin_amdgcn_sched_barrier(0);
        const char* base = lds + buf * 24576;
        f16x8 a[4], bf[2];
        #pragma unroll
        for (int st = 0; st < 4; ++st) {
            int srow = st * 16 + (lane & 15);
            int schunk = (srow >> 3) ^ (g << 1);
            int off = wv * 4096 + g * 1024 + (schunk << 4) + (srow & 7) * 2;
            #pragma unroll
            for (int j = 0; j < 8; ++j)
                a[st][j] = *(const f16*)(base + off + j * 128);
        }
        #pragma unroll
        for (int dt = 0; dt < 2; ++dt) {
            int d = dt * 16 + (lane & 15);
            int dchunk = ((d >> 3) ^ g) & 3;
            int off = 16384 + wv * 2048 + g * 512 + (dchunk << 4) + (d & 7) * 2;
            #pragma unroll
            for (int j = 0; j < 8; ++j)
                bf[dt][j] = *(const f16*)(base + off + j * 64);
        }
        #pragma unroll
        for (int st = 0; st < 4; ++st) {
            acc[st][0] = __builtin_amdgcn_mfma_f32_16x16x32_f16(a[st], bf[0], acc[st][0], 0, 0, 0);
            acc[st][1] = __builtin_amdgcn_mfma_f32_16x16x32_f16(a[st], bf[1], acc[st][1], 0, 0, 0);
            acc[st][2] = __builtin_amdgcn_mfma_f32_16x16x32_f16(a[st], bones, acc[st][2], 0, 0, 0);
        }
    }
    __syncthreads();
    float* red = (float*)lds;
    #pragma unroll
    for (int st = 0; st < 4; ++st) {
        #pragma unroll
        for (int rr = 0; rr < 4; ++rr) {
            int s = st * 16 + g * 4 + rr;
            red[(wv * 64 + s) * 36 + (lane & 15)] = acc[st][0][rr];
            red[(wv * 64 + s) * 36 + 16 + (lane & 15)] = acc[st][1][rr];
            if ((lane & 15) == 0)
                red[(wv * 64 + s) * 36 + 32] = acc[st][2][rr];
        }
    }
    __syncthreads();
    float* P = partials + ((long)bh * 64 + chunk64) * 2112;
    for (int idx = tid; idx < 2112; idx += 256) {
        int s, c;
        if (idx < 2048) { s = idx >> 5; c = idx & 31; }
        else            { s = idx - 2048; c = 32; }
        float v = red[s * 36 + c] + red[(64 + s) * 36 + c]
                + red[(128 + s) * 36 + c] + red[(192 + s) * 36 + c];
        P[idx] = v;
    }
}

// ---------------- K3: reduce partials, slice attention, build OT2T (f16) ----------------
__global__ __launch_bounds__(256) void k3_slice(
    const float* __restrict__ partials,
    const float* __restrict__ Wqkv,
    const float* __restrict__ Wout,
    f16* __restrict__ OT2T)
{
    __shared__ float smem[14720];
    float* st = smem;          // 64*33
    float* q  = smem + 2112;
    float* kk = smem + 4224;
    float* v  = smem + 6336;
    float* L  = smem + 8448;   // 64*65
    float* red = L;
    float* ot = smem + 12608;  // 64*33

    int bh = blockIdx.x;
    int b = bh >> 3, h = bh & 7;
    int tid = threadIdx.x;

    for (int idx = tid; idx < 2112; idx += 256) {
        float s = 0.f;
        const float* P = partials + (long)bh * 64 * 2112 + idx;
        for (int c = 0; c < 64; ++c) s += P[c * 2112];
        red[idx] = s;
    }
    __syncthreads();
    for (int idx = tid; idx < 2048; idx += 256) {
        int s = idx >> 5, d = idx & 31;
        st[s * 33 + d] = red[idx] / (red[2048 + s] + 0.01f);
    }
    __syncthreads();
    for (int idx = tid; idx < 64 * 96; idx += 256) {
        int s = idx / 96, e = idx % 96;
        float acc = 0.f;
        #pragma unroll
        for (int d = 0; d < 32; ++d) acc += st[s * 33 + d] * Wqkv[e * 32 + d];
        if (e < 32)       q[s * 33 + e] = acc;
        else if (e < 64)  kk[s * 33 + (e - 32)] = acc;
        else              v[s * 33 + (e - 64)] = acc;
    }
    __syncthreads();
    for (int idx = tid; idx < 4096; idx += 256) {
        int i = idx >> 6, j = idx & 63;
        float acc = 0.f;
        #pragma unroll
        for (int d = 0; d < 32; ++d) acc += q[i * 33 + d] * kk[j * 33 + d];
        L[i * 65 + j] = acc * 0.17677669529663687f;
    }
    __syncthreads();
    {
        int lane = tid & 63, wid = tid >> 6;
        for (int r = wid; r < 64; r += 4) {
            float x = L[r * 65 + lane];
            float m = x;
            #pragma unroll
            for (int o = 32; o; o >>= 1) m = fmaxf(m, __shfl_xor(m, o));
            float e = __expf(x - m);
            float ss2 = e;
            #pragma unroll
            for (int o = 32; o; o >>= 1) ss2 += __shfl_xor(ss2, o);
            L[r * 65 + lane] = e / ss2;
        }
    }
    __syncthreads();
    for (int idx = tid; idx < 2048; idx += 256) {
        int s = idx >> 5, d = idx & 31;
        float acc = 0.f;
        #pragma unroll
        for (int j = 0; j < 64; ++j) acc += L[s * 65 + j] * v[j * 33 + d];
        ot[s * 33 + d] = acc;
    }
    __syncthreads();
    float* Wo = smem;  // 256*33
    for (int idx = tid; idx < 8192; idx += 256) {
        int c = idx >> 5, d = idx & 31;
        Wo[c * 33 + d] = Wout[c * 256 + h * 32 + d];
    }
    __syncthreads();
    {
        int c = tid;
        f16* O = OT2T + (long)b * 131072 + (long)c * 512 + h * 64;
        for (int s = 0; s < 64; ++s) {
            float acc = 0.f;
            #pragma unroll
            for (int d = 0; d < 32; ++d) acc += ot[s * 33 + d] * Wo[c * 33 + d];
            O[s] = (f16)acc;
        }
    }
}

extern "C" void kernel_launch(void* const* d_in, const int* in_sizes, int n_in,
                              void* d_out, int out_size, void* d_ws, size_t ws_size,
                              hipStream_t stream) {
    const float* x           = (const float*)d_in[0];
    const float* Wx          = (const float*)d_in[1];
    const float* bx          = (const float*)d_in[2];
    const float* Wfx         = (const float*)d_in[3];
    const float* bfx         = (const float*)d_in[4];
    const float* Wslice      = (const float*)d_in[5];
    const float* bslice      = (const float*)d_in[6];
    const float* Wqkv        = (const float*)d_in[7];
    const float* Wout        = (const float*)d_in[8];
    const float* bout        = (const float*)d_in[9];
    const float* temperature = (const float*)d_in[10];
    float* out = (float*)d_out;

    char* ws = (char*)d_ws;
    f16*   yfx      = (f16*)(ws);                    // 131072*256 f16  =  67108864 B
    f16*   yw       = (f16*)(ws + 67108864ULL);      // 131072*512 f16  = 134217728 B
    float* partials = (float*)(ws + 201326592ULL);   // 32*64*2112 f32  =  17301504 B
    f16*   Bt       = (f16*)(ws + 218628096ULL);     // 768*256 f16     =    393216 B
    float* bcomb    = (float*)(ws + 219021312ULL);   // 768 f32         =      3072 B
    f16*   OT2T     = (f16*)(ws + 219024384ULL);     // 4*256*512 f16   =   1048576 B (end 220072960)

    // K0: combined weights (f16, [n][k] layout)
    k0_build<<<768, 256, 0, stream>>>(Wx, bx, Wfx, bfx, Wslice, bslice, Bt, bcomb);

    // K1a: [fx | w] = x @ Bcomb + bcomb, softmax fused; A = fp32 x reg-staged
    //      (xcvt pass deleted), B via gload_lds, 3-buf counted-vmcnt pipeline
    gemm_wx<8><<<dim3(NCOL / 256, BNT / 128), 512, 0, stream>>>(
        x, Bt, bcomb, yfx, yw, temperature);

    // K1c: pooled partial sums via MFMA (barrier-free, counted vmcnt)
    k1c_mfma<<<32 * 64, 256, 0, stream>>>(yfx, yw, partials);

    // K3: slice attention + OT2T (f16 transposed)
    k3_slice<<<32, 256, 0, stream>>>(partials, Wqkv, Wout, OT2T);

    // K4: out = w @ OT2 + bout (M=131072, N=256, K=512), round-10 gemm_w
    gemm_w<16><<<dim3(1, BNT / 128), 512, 0, stream>>>(
        yw, OT2T, bout, out, 131072L);
}

// Round 15
// 348.811 us; speedup vs baseline: 1.0291x; 1.0291x over previous
//
#include <hip/hip_runtime.h>

// Dims
#define NB 4
#define NTOK 32768
#define BNT 131072      // NB*NTOK
#define CDIM 256
#define HH 8
#define NCOL 768        // 256 fx cols + 512 proj cols

typedef _Float16 f16;
typedef __attribute__((ext_vector_type(8))) _Float16 f16x8;
typedef __attribute__((ext_vector_type(4))) _Float16 f16x4;
typedef __attribute__((ext_vector_type(4))) float f32x4;

__device__ inline void gload_lds16(const void* g, void* l) {
    __builtin_amdgcn_global_load_lds(
        (const __attribute__((address_space(1))) void*)g,
        (__attribute__((address_space(3))) void*)l, 16, 0, 0);
}

// ---------------- K0x: fused weight-build + x->f16 convert ----------------
// blocks [0,768): Bt row build (f16, transposed combined weight) + bcomb
// blocks [768, 768+2048): grid-stride x fp32 -> f16 convert
__global__ __launch_bounds__(256) void k0x(
    const float* __restrict__ Wx, const float* __restrict__ bx,
    const float* __restrict__ Wfx, const float* __restrict__ bfx,
    const float* __restrict__ Wslice, const float* __restrict__ bslice,
    f16* __restrict__ Bt, float* __restrict__ bcomb,
    const float* __restrict__ x, f16* __restrict__ xf)
{
    int bid = blockIdx.x;
    if (bid < 768) {
        int col = bid;             // output column n
        int k = threadIdx.x;       // input channel
        float acc;
        if (col < 256) {
            acc = Wfx[col * 256 + k];
            if (k == 0) bcomb[col] = bfx[col];
        } else {
            int p = col - 256, h = p >> 6, s = p & 63;
            acc = 0.f;
            #pragma unroll
            for (int d = 0; d < 32; ++d)
                acc += Wx[(h * 32 + d) * 256 + k] * Wslice[s * 32 + d];
            if (k == 0) {
                float bacc = bslice[s];
                #pragma unroll
                for (int d = 0; d < 32; ++d)
                    bacc += bx[h * 32 + d] * Wslice[s * 32 + d];
                bcomb[col] = bacc;
            }
        }
        Bt[(long)col * 256 + k] = (f16)acc;
    } else {
        long i = (long)(bid - 768) * 256 + threadIdx.x;
        const long stride = 2048L * 256;
        const long n4 = (long)BNT * CDIM / 4;
        for (; i < n4; i += stride) {
            float4 v = ((const float4*)x)[i];
            f16x4 o = {(f16)v.x, (f16)v.y, (f16)v.z, (f16)v.w};
            *(f16x4*)(xf + i * 4) = o;
        }
    }
}

// ---------------- wide GEMM: 128m x 256n tile, 512 thr (8 waves 2x4), BK=32 ----
// A f16 [M][KO], Bt f16 [N][KO]. 3-buffer LDS (24KB/step), depth-2 prefetch,
// counted vmcnt(3) + raw s_barrier (loads stay in flight across barriers).
// BK=32 rows (64B): XOR chunk ^= (r>>1)&3 (2-way residual = free), source
// pre-swizzled for gload_lds. XCD-bijective block swizzle (nwg%8==0).
// FUSE_SM: n0==0 -> f16 fx to Cfx[ld 256]; n0>0 -> temp-softmax per 64-col
// head block, f16 to Cw[ld 512]. Else fp32 to Cf[ld 256].
template<int NSO, bool FUSE_SM>
__global__ __launch_bounds__(512) void gemm_w(
    const f16* __restrict__ A, const f16* __restrict__ Bt,
    const float* __restrict__ bias, float* __restrict__ Cf,
    f16* __restrict__ Cfx, f16* __restrict__ Cw,
    const float* __restrict__ temperature, long bStrideB)
{
    constexpr int KO = NSO * 32;
    __shared__ char lds[73728];   // 3 x (A 8KB | B 16KB)

    const int tid = threadIdx.x;
    const int lane = tid & 63;
    const int w = tid >> 6;        // 0..7
    const int wm = w >> 2, wn = w & 3;

    // XCD-aware bijective swizzle
    const int nx = gridDim.x;
    const int nwg = nx * gridDim.y;
    const int lid = blockIdx.y * nx + blockIdx.x;
    const int swz = (lid & 7) * (nwg >> 3) + (lid >> 3);
    const int m0 = (swz / nx) * 128, n0 = (swz % nx) * 256;

    const f16* BtB = Bt + ((long)m0 >> 15) * bStrideB;  // per-batch B (K4)

    f32x4 acc[4][4] = {};

    auto stage = [&](int cs, int buf) {
        char* base = lds + buf * 24576;
        {   // A slot: chunk q = tid; r=q>>2 in 0..127, c=q&3
            int r = tid >> 2, c = tid & 3;
            int csrc = c ^ ((r >> 1) & 3);
            gload_lds16(A + (long)(m0 + r) * KO + cs * 32 + csrc * 8,
                        base + (tid & ~63) * 16);
        }
        #pragma unroll
        for (int i = 0; i < 2; ++i) {   // B slots (2 per wave): r in 0..255
            int q = (w * 2 + i) * 64 + lane;
            int r = q >> 2, c = q & 3;
            int csrc = c ^ ((r >> 1) & 3);
            gload_lds16(BtB + (long)(n0 + r) * KO + cs * 32 + csrc * 8,
                        base + 8192 + (w * 2 + i) * 1024);
        }
    };

    stage(0, 0);
    stage(1, 1);
    asm volatile("s_waitcnt vmcnt(3)" ::: "memory");   // tile 0 landed
    __builtin_amdgcn_sched_barrier(0);
    __builtin_amdgcn_s_barrier();

    for (int cs = 0; cs < NSO; ++cs) {
        const int buf = cs % 3;
        if (cs + 2 < NSO) stage(cs + 2, (cs + 2) % 3);
        const char* sa = lds + buf * 24576;
        const char* sb = sa + 8192;
        const int cr = lane >> 4;
        f16x8 a[4], b[4];
        #pragma unroll
        for (int mi = 0; mi < 4; ++mi) {
            int r = wm * 64 + mi * 16 + (lane & 15);
            a[mi] = *(const f16x8*)(sa + r * 64 + ((cr ^ ((r >> 1) & 3)) << 4));
        }
        #pragma unroll
        for (int ni = 0; ni < 4; ++ni) {
            int r = wn * 64 + ni * 16 + (lane & 15);
            b[ni] = *(const f16x8*)(sb + r * 64 + ((cr ^ ((r >> 1) & 3)) << 4));
        }
        #pragma unroll
        for (int mi = 0; mi < 4; ++mi)
            #pragma unroll
            for (int ni = 0; ni < 4; ++ni)
                acc[mi][ni] = __builtin_amdgcn_mfma_f32_16x16x32_f16(
                    a[mi], b[ni], acc[mi][ni], 0, 0, 0);
        if (cs + 1 < NSO) {
            if (cs + 2 < NSO) asm volatile("s_waitcnt vmcnt(3)" ::: "memory");
            else              asm volatile("s_waitcnt vmcnt(0)" ::: "memory");
            __builtin_amdgcn_sched_barrier(0);
            __builtin_amdgcn_s_barrier();
        }
    }

    // --- epilogue: C/D layout col=lane&15, row=(lane>>4)*4+reg ---
    {
        int rbase = m0 + wm * 64 + (lane >> 4) * 4;
        int cbase = n0 + wn * 64 + (lane & 15);
        float bv[4];
        #pragma unroll
        for (int ni = 0; ni < 4; ++ni) bv[ni] = bias[cbase + ni * 16];

        if constexpr (FUSE_SM) {
            if (n0 > 0) {   // proj cols; wave's 64-col span = one head
                int h = ((n0 - 256) >> 6) + wn;
                float invt = 1.f / fminf(fmaxf(temperature[h], 0.5f), 5.0f);
                #pragma unroll
                for (int mi = 0; mi < 4; ++mi)
                    #pragma unroll
                    for (int rr = 0; rr < 4; ++rr) {
                        float v[4];
                        #pragma unroll
                        for (int ni = 0; ni < 4; ++ni)
                            v[ni] = (acc[mi][ni][rr] + bv[ni]) * invt;
                        float m = fmaxf(fmaxf(v[0], v[1]), fmaxf(v[2], v[3]));
                        #pragma unroll
                        for (int o = 1; o < 16; o <<= 1) m = fmaxf(m, __shfl_xor(m, o));
                        float e[4], ssum = 0.f;
                        #pragma unroll
                        for (int ni = 0; ni < 4; ++ni) { e[ni] = __expf(v[ni] - m); ssum += e[ni]; }
                        #pragma unroll
                        for (int o = 1; o < 16; o <<= 1) ssum += __shfl_xor(ssum, o);
                        float rs = 1.f / ssum;
                        long row = rbase + mi * 16 + rr;
                        #pragma unroll
                        for (int ni = 0; ni < 4; ++ni)
                            Cw[row * 512 + cbase + ni * 16 - 256] = (f16)(e[ni] * rs);
                    }
            } else {        // fx cols
                #pragma unroll
                for (int mi = 0; mi < 4; ++mi)
                    #pragma unroll
                    for (int rr = 0; rr < 4; ++rr) {
                        long row = rbase + mi * 16 + rr;
                        #pragma unroll
                        for (int ni = 0; ni < 4; ++ni)
                            Cfx[row * 256 + cbase + ni * 16] =
                                (f16)(acc[mi][ni][rr] + bv[ni]);
                    }
            }
        } else {
            #pragma unroll
            for (int mi = 0; mi < 4; ++mi)
                #pragma unroll
                for (int ni = 0; ni < 4; ++ni)
                    #pragma unroll
                    for (int rr = 0; rr < 4; ++rr)
                        Cf[(long)(rbase + mi * 16 + rr) * 256 + cbase + ni * 16] =
                            acc[mi][ni][rr] + bv[ni];
        }
    }
}

// ---------------- K1c (MFMA): slice_token + slice_norm partials via matrix pipe ----
__global__ __launch_bounds__(256) void k1c_mfma(
    const f16* __restrict__ yfx, const f16* __restrict__ yw,
    float* __restrict__ partials)
{
    __shared__ char lds[49152];

    const int tid = threadIdx.x;
    const int lane = tid & 63;
    const int wv = tid >> 6;
    const int chunk64 = blockIdx.x & 63;
    const int bh = blockIdx.x >> 6;
    const int b = bh >> 3, h = bh & 7;
    const long tbase = (long)b * NTOK + (long)chunk64 * 512;

    f32x4 acc[4][3] = {};

    const f16 oe = ((lane & 15) == 0) ? (f16)1.0f : (f16)0.0f;
    const f16x8 bones = {oe, oe, oe, oe, oe, oe, oe, oe};
    const int g = lane >> 4;

    auto stage = [&](int iter, int buf) {
        const long t0 = tbase + iter * 128;
        char* base = lds + buf * 24576;
        #pragma unroll
        for (int i = 0; i < 4; ++i) {
            int k = wv * 4 + i;
            int sc = (lane & 7) ^ ((k & 3) << 1);
            gload_lds16(yw + (t0 + k * 8 + (lane >> 3)) * 512 + h * 64 + sc * 8,
                        base + k * 1024);
        }
        #pragma unroll
        for (int i = 0; i < 2; ++i) {
            int k = wv * 2 + i;
            int tq = (k & 1) * 16 + (lane >> 2);
            int dc = (lane & 3) ^ ((tq >> 3) & 3);
            gload_lds16(yfx + (t0 + k * 16 + (lane >> 2)) * 256 + h * 32 + dc * 8,
                        base + 16384 + k * 1024);
        }
    };

    stage(0, 0);
    for (int iter = 0; iter < 4; ++iter) {
        const int buf = iter & 1;
        if (iter < 3) {
            stage(iter + 1, buf ^ 1);
            asm volatile("s_waitcnt vmcnt(6)" ::: "memory");
        } else {
            asm volatile("s_waitcnt vmcnt(0)" ::: "memory");
        }
        __builtin_amdgcn_sched_barrier(0);
        const char* base = lds + buf * 24576;
        f16x8 a[4], bf[2];
        #pragma unroll
        for (int st = 0; st < 4; ++st) {
            int srow = st * 16 + (lane & 15);
            int schunk = (srow >> 3) ^ (g << 1);
            int off = wv * 4096 + g * 1024 + (schunk << 4) + (srow & 7) * 2;
            #pragma unroll
            for (int j = 0; j < 8; ++j)
                a[st][j] = *(const f16*)(base + off + j * 128);
        }
        #pragma unroll
        for (int dt = 0; dt < 2; ++dt) {
            int d = dt * 16 + (lane & 15);
            int dchunk = ((d >> 3) ^ g) & 3;
            int off = 16384 + wv * 2048 + g * 512 + (dchunk << 4) + (d & 7) * 2;
            #pragma unroll
            for (int j = 0; j < 8; ++j)
                bf[dt][j] = *(const f16*)(base + off + j * 64);
        }
        #pragma unroll
        for (int st = 0; st < 4; ++st) {
            acc[st][0] = __builtin_amdgcn_mfma_f32_16x16x32_f16(a[st], bf[0], acc[st][0], 0, 0, 0);
            acc[st][1] = __builtin_amdgcn_mfma_f32_16x16x32_f16(a[st], bf[1], acc[st][1], 0, 0, 0);
            acc[st][2] = __builtin_amdgcn_mfma_f32_16x16x32_f16(a[st], bones, acc[st][2], 0, 0, 0);
        }
    }
    __syncthreads();
    float* red = (float*)lds;
    #pragma unroll
    for (int st = 0; st < 4; ++st) {
        #pragma unroll
        for (int rr = 0; rr < 4; ++rr) {
            int s = st * 16 + g * 4 + rr;
            red[(wv * 64 + s) * 36 + (lane & 15)] = acc[st][0][rr];
            red[(wv * 64 + s) * 36 + 16 + (lane & 15)] = acc[st][1][rr];
            if ((lane & 15) == 0)
                red[(wv * 64 + s) * 36 + 32] = acc[st][2][rr];
        }
    }
    __syncthreads();
    float* P = partials + ((long)bh * 64 + chunk64) * 2112;
    for (int idx = tid; idx < 2112; idx += 256) {
        int s, c;
        if (idx < 2048) { s = idx >> 5; c = idx & 31; }
        else            { s = idx - 2048; c = 32; }
        float v = red[s * 36 + c] + red[(64 + s) * 36 + c]
                + red[(128 + s) * 36 + c] + red[(192 + s) * 36 + c];
        P[idx] = v;
    }
}

// ---------------- K3: reduce partials, slice attention, build OT2T (f16) ----------------
__global__ __launch_bounds__(256) void k3_slice(
    const float* __restrict__ partials,
    const float* __restrict__ Wqkv,
    const float* __restrict__ Wout,
    f16* __restrict__ OT2T)
{
    __shared__ float smem[14720];
    float* st = smem;          // 64*33
    float* q  = smem + 2112;
    float* kk = smem + 4224;
    float* v  = smem + 6336;
    float* L  = smem + 8448;   // 64*65
    float* red = L;
    float* ot = smem + 12608;  // 64*33

    int bh = blockIdx.x;
    int b = bh >> 3, h = bh & 7;
    int tid = threadIdx.x;

    for (int idx = tid; idx < 2112; idx += 256) {
        float s = 0.f;
        const float* P = partials + (long)bh * 64 * 2112 + idx;
        for (int c = 0; c < 64; ++c) s += P[c * 2112];
        red[idx] = s;
    }
    __syncthreads();
    for (int idx = tid; idx < 2048; idx += 256) {
        int s = idx >> 5, d = idx & 31;
        st[s * 33 + d] = red[idx] / (red[2048 + s] + 0.01f);
    }
    __syncthreads();
    for (int idx = tid; idx < 64 * 96; idx += 256) {
        int s = idx / 96, e = idx % 96;
        float acc = 0.f;
        #pragma unroll
        for (int d = 0; d < 32; ++d) acc += st[s * 33 + d] * Wqkv[e * 32 + d];
        if (e < 32)       q[s * 33 + e] = acc;
        else if (e < 64)  kk[s * 33 + (e - 32)] = acc;
        else              v[s * 33 + (e - 64)] = acc;
    }
    __syncthreads();
    for (int idx = tid; idx < 4096; idx += 256) {
        int i = idx >> 6, j = idx & 63;
        float acc = 0.f;
        #pragma unroll
        for (int d = 0; d < 32; ++d) acc += q[i * 33 + d] * kk[j * 33 + d];
        L[i * 65 + j] = acc * 0.17677669529663687f;
    }
    __syncthreads();
    {
        int lane = tid & 63, wid = tid >> 6;
        for (int r = wid; r < 64; r += 4) {
            float x = L[r * 65 + lane];
            float m = x;
            #pragma unroll
            for (int o = 32; o; o >>= 1) m = fmaxf(m, __shfl_xor(m, o));
            float e = __expf(x - m);
            float ss2 = e;
            #pragma unroll
            for (int o = 32; o; o >>= 1) ss2 += __shfl_xor(ss2, o);
            L[r * 65 + lane] = e / ss2;
        }
    }
    __syncthreads();
    for (int idx = tid; idx < 2048; idx += 256) {
        int s = idx >> 5, d = idx & 31;
        float acc = 0.f;
        #pragma unroll
        for (int j = 0; j < 64; ++j) acc += L[s * 65 + j] * v[j * 33 + d];
        ot[s * 33 + d] = acc;
    }
    __syncthreads();
    float* Wo = smem;  // 256*33
    for (int idx = tid; idx < 8192; idx += 256) {
        int c = idx >> 5, d = idx & 31;
        Wo[c * 33 + d] = Wout[c * 256 + h * 32 + d];
    }
    __syncthreads();
    {
        int c = tid;
        f16* O = OT2T + (long)b * 131072 + (long)c * 512 + h * 64;
        for (int s = 0; s < 64; ++s) {
            float acc = 0.f;
            #pragma unroll
            for (int d = 0; d < 32; ++d) acc += ot[s * 33 + d] * Wo[c * 33 + d];
            O[s] = (f16)acc;
        }
    }
}

extern "C" void kernel_launch(void* const* d_in, const int* in_sizes, int n_in,
                              void* d_out, int out_size, void* d_ws, size_t ws_size,
                              hipStream_t stream) {
    const float* x           = (const float*)d_in[0];
    const float* Wx          = (const float*)d_in[1];
    const float* bx          = (const float*)d_in[2];
    const float* Wfx         = (const float*)d_in[3];
    const float* bfx         = (const float*)d_in[4];
    const float* Wslice      = (const float*)d_in[5];
    const float* bslice      = (const float*)d_in[6];
    const float* Wqkv        = (const float*)d_in[7];
    const float* Wout        = (const float*)d_in[8];
    const float* bout        = (const float*)d_in[9];
    const float* temperature = (const float*)d_in[10];
    float* out = (float*)d_out;

    char* ws = (char*)d_ws;
    f16*   xf16     = (f16*)(ws);                     // 131072*256 f16  =  67108864 B
    f16*   yfx      = (f16*)(ws + 67108864ULL);      // 131072*256 f16  =  67108864 B
    f16*   yw       = (f16*)(ws + 134217728ULL);     // 131072*512 f16  = 134217728 B
    float* partials = (float*)(ws + 268435456ULL);   // 32*64*2112 f32  =  17301504 B
    f16*   Bt       = (f16*)(ws + 285736960ULL);     // 768*256 f16     =    393216 B
    float* bcomb    = (float*)(ws + 286130176ULL);   // 768 f32         =      3072 B
    f16*   OT2T     = (f16*)(ws + 286133248ULL);     // 4*256*512 f16   =   1048576 B (end 287181824)

    // K0x: combined weights (f16) + x -> f16 convert, fused
    k0x<<<768 + 2048, 256, 0, stream>>>(Wx, bx, Wfx, bfx, Wslice, bslice,
                                        Bt, bcomb, x, xf16);

    // K1a: [fx | w] = x @ Bcomb + bcomb, softmax fused; 128x256 tiles,
    //      8 waves, BK=32, 3-buffer counted-vmcnt pipeline (round-10 proven)
    gemm_w<8, true><<<dim3(NCOL / 256, BNT / 128), 512, 0, stream>>>(
        xf16, Bt, bcomb, nullptr, yfx, yw, temperature, 0L);

    // K1c: pooled partial sums via MFMA (barrier-free, counted vmcnt)
    k1c_mfma<<<32 * 64, 256, 0, stream>>>(yfx, yw, partials);

    // K3: slice attention + OT2T (f16 transposed)
    k3_slice<<<32, 256, 0, stream>>>(partials, Wqkv, Wout, OT2T);

    // K4: out = w @ OT2 + bout (M=131072, N=256, K=512), single n-tile/block
    gemm_w<16, false><<<dim3(1, BNT / 128), 512, 0, stream>>>(
        yw, OT2T, bout, out, nullptr, nullptr, nullptr, 131072L);
}